// Round 7
// baseline (617.812 us; speedup 1.0000x reference)
//
#include <hip/hip_runtime.h>
#include <hip/hip_fp16.h>

#define N_NODES 100000
#define N_EDGES 1600000
#define HID 128
#define N_GRAPHS 512
#define SCAN_B 256

typedef _Float16 f16x8 __attribute__((ext_vector_type(8)));
typedef float f32x4 __attribute__((ext_vector_type(4)));

// ---------------- CSR build: histogram / scan / scatter ----------------

__global__ void k_hist(const int* __restrict__ dst, int e, int* __restrict__ cnt) {
    int i = blockIdx.x * 256 + threadIdx.x;
    if (i < e) atomicAdd(&cnt[dst[i]], 1);
}

__global__ void k_deg_fin(const int* __restrict__ cnt, float* __restrict__ dis,
                          float* __restrict__ dinv, int n) {
    int i = blockIdx.x * 256 + threadIdx.x;
    if (i < n) {
        float d = (float)(cnt[i] + 1);   // +1 self-loop
        dis[i] = rsqrtf(d);
        dinv[i] = 1.0f / d;
    }
}

__global__ void k_scan1(const int* __restrict__ cnt, int* __restrict__ pre,
                        int* __restrict__ bsum, int n) {
    __shared__ int s[SCAN_B];
    int t = threadIdx.x;
    int i = blockIdx.x * SCAN_B + t;
    int v = (i < n) ? cnt[i] : 0;
    s[t] = v;
    __syncthreads();
    for (int off = 1; off < SCAN_B; off <<= 1) {
        int u = (t >= off) ? s[t - off] : 0;
        __syncthreads();
        s[t] += u;
        __syncthreads();
    }
    if (i < n) pre[i] = s[t] - v;                     // exclusive
    if (t == SCAN_B - 1) bsum[blockIdx.x] = s[t];     // block total
}

__global__ void k_scan2(int* __restrict__ bsum, int nb) {
    __shared__ int s[512];
    int t = threadIdx.x;
    int v = (t < nb) ? bsum[t] : 0;
    s[t] = v;
    __syncthreads();
    for (int off = 1; off < 512; off <<= 1) {
        int u = (t >= off) ? s[t - off] : 0;
        __syncthreads();
        s[t] += u;
        __syncthreads();
    }
    if (t < nb) bsum[t] = s[t] - v;                   // exclusive
}

__global__ void k_scan3(int* __restrict__ pre, const int* __restrict__ bsum,
                        int* __restrict__ cursor, int n, int e) {
    int i = blockIdx.x * SCAN_B + threadIdx.x;
    if (i < n) {
        int r = pre[i] + bsum[blockIdx.x];
        pre[i] = r;
        cursor[i] = r;
    }
    if (i == 0) pre[n] = e;
}

// scatter: random 4B plain stores cost a 64B HBM line each (R6: WRITE_SIZE
// = 1.6M x 64B). Atomics execute near-memory in the TCC at payload size
// (R1 evidence: 410M atomicAdds -> WRITE_SIZE exactly 4B each). So emit the
// scatter store as atomicExch — same value, ~8x less HBM write traffic.
__global__ void k_scatter(const int* __restrict__ ei, int* __restrict__ cursor,
                          int* __restrict__ csrc, int e) {
    int i = blockIdx.x * 256 + threadIdx.x;
    if (i >= e) return;
    int s = ei[i];
    int d = ei[N_EDGES + i];
    int pos = atomicAdd(&cursor[d], 1);
    atomicExch(&csrc[pos], s);
}

// ---------------- layer 1: x (N x 7) @ W1 (7 x 128) -> fp16 ----------------

__global__ void k_linear1(const float* __restrict__ x, const float* __restrict__ W1,
                          __half* __restrict__ hw, int n) {
    __shared__ float W1s[7 * 128];
    int tid = threadIdx.x;
    for (int i = tid; i < 7 * 128; i += 256) W1s[i] = W1[i];
    __syncthreads();
    int node = blockIdx.x * 2 + (tid >> 7);
    if (node >= n) return;
    int c = tid & 127;
    const float* xr = x + (size_t)node * 7;
    float acc = 0.f;
#pragma unroll
    for (int k = 0; k < 7; ++k) acc += xr[k] * W1s[k * 128 + c];
    hw[(size_t)node * 128 + c] = __float2half_rn(acc);
}

// ---------------- gather aggregation (fp16 rows) ----------------
// agg[d] = dinv[d]*hw[d] + dis[d] * sum_s dis[s]*hw[s]
// One wave per node; cooperative preload of indices/weights, __shfl broadcast.

__launch_bounds__(256) __global__
void k_gather(const int* __restrict__ rowptr, const int* __restrict__ csrc,
              const float* __restrict__ dis, const float* __restrict__ dinv,
              const __half2* __restrict__ hw2, __half2* __restrict__ agg2, int n) {
    int node = blockIdx.x * 4 + (threadIdx.x >> 6);
    if (node >= n) return;
    int lane = threadIdx.x & 63;
    int beg = rowptr[node];
    int end = rowptr[node + 1];
    int deg = end - beg;
    float dd = dis[node];
    float di = dinv[node];
    float2 hv = __half22float2(hw2[(size_t)node * 64 + lane]);
    float accx = hv.x * di;
    float accy = hv.y * di;

    int sidx = 0;
    float wsc = 0.f;
    if (lane < deg) {
        sidx = csrc[beg + lane];
        wsc = dis[sidx];
    }

    float sx = 0.f, sy = 0.f;
    int m = deg < 64 ? deg : 64;
    int j = 0;
    for (; j + 3 < m; j += 4) {
        int s0 = __shfl(sidx, j);     float w0 = __shfl(wsc, j);
        int s1 = __shfl(sidx, j + 1); float w1 = __shfl(wsc, j + 1);
        int s2 = __shfl(sidx, j + 2); float w2 = __shfl(wsc, j + 2);
        int s3 = __shfl(sidx, j + 3); float w3 = __shfl(wsc, j + 3);
        float2 v0 = __half22float2(hw2[(size_t)s0 * 64 + lane]);
        float2 v1 = __half22float2(hw2[(size_t)s1 * 64 + lane]);
        float2 v2 = __half22float2(hw2[(size_t)s2 * 64 + lane]);
        float2 v3 = __half22float2(hw2[(size_t)s3 * 64 + lane]);
        sx += v0.x * w0 + v1.x * w1 + v2.x * w2 + v3.x * w3;
        sy += v0.y * w0 + v1.y * w1 + v2.y * w2 + v3.y * w3;
    }
    for (; j < m; ++j) {
        int s0 = __shfl(sidx, j);
        float w0 = __shfl(wsc, j);
        float2 v0 = __half22float2(hw2[(size_t)s0 * 64 + lane]);
        sx += v0.x * w0;
        sy += v0.y * w0;
    }
    for (int jj = beg + 64; jj < end; ++jj) {
        int s0 = csrc[jj];
        float w0 = dis[s0];
        float2 v0 = __half22float2(hw2[(size_t)s0 * 64 + lane]);
        sx += v0.x * w0;
        sy += v0.y * w0;
    }
    accx += dd * sx;
    accy += dd * sy;
    agg2[(size_t)node * 64 + lane] = __floats2half2_rn(accx, accy);
}

// ---------------- MFMA GEMM: hwout = relu(aggin + b) @ W  (fp16 in/out) ----------------
// 4 waves/block; W^T staged once, two 64-row A-tiles per block. XOR swizzle
// kills bank conflicts. Rows >= n zero-filled (no OOB read of poisoned ws).

__device__ __forceinline__ int swz(int row, int kByte) {
    return row * 256 + (kByte ^ ((row & 7) << 4));
}

__launch_bounds__(256) __global__
void k_gemm_mfma(const __half* __restrict__ aggin, const float* __restrict__ b,
                 const float* __restrict__ W, __half* __restrict__ hwout, int n) {
    __shared__ __align__(16) _Float16 Wt[128 * 128];  // 32 KB
    __shared__ __align__(16) _Float16 As[64 * 128];   // 16 KB
    int tid = threadIdx.x;

    for (int i = tid; i < 128 * 128; i += 256) {
        int k = i >> 7;
        int nn = i & 127;
        *(_Float16*)((char*)Wt + swz(nn, k * 2)) = (_Float16)W[i];
    }

    int row = tid >> 2;
    int q = tid & 3;
    int wv = tid >> 6;
    int lane = tid & 63;
    int lo16 = lane & 15;
    int hi4 = lane >> 4;

    for (int t = 0; t < 2; ++t) {
        if (t) __syncthreads();
        int grow = blockIdx.x * 128 + t * 64 + row;
#pragma unroll
        for (int j = 0; j < 4; ++j) {
            int c0 = q * 32 + j * 8;
            uint4 pk = make_uint4(0u, 0u, 0u, 0u);
            if (grow < n) {
                uint4 p = *(const uint4*)(aggin + (size_t)grow * 128 + c0);
                float4 bA = *(const float4*)(b + c0);
                float4 bB = *(const float4*)(b + c0 + 4);
                float2 t0 = __half22float2(*(const __half2*)&p.x);
                float2 t1 = __half22float2(*(const __half2*)&p.y);
                float2 t2 = __half22float2(*(const __half2*)&p.z);
                float2 t3 = __half22float2(*(const __half2*)&p.w);
                __half2 h0 = __floats2half2_rn(fmaxf(t0.x + bA.x, 0.f), fmaxf(t0.y + bA.y, 0.f));
                __half2 h1 = __floats2half2_rn(fmaxf(t1.x + bA.z, 0.f), fmaxf(t1.y + bA.w, 0.f));
                __half2 h2 = __floats2half2_rn(fmaxf(t2.x + bB.x, 0.f), fmaxf(t2.y + bB.y, 0.f));
                __half2 h3 = __floats2half2_rn(fmaxf(t3.x + bB.z, 0.f), fmaxf(t3.y + bB.w, 0.f));
                pk.x = *(unsigned*)&h0; pk.y = *(unsigned*)&h1;
                pk.z = *(unsigned*)&h2; pk.w = *(unsigned*)&h3;
            }
            *(uint4*)((char*)As + swz(row, c0 * 2)) = pk;
        }
        __syncthreads();

        f32x4 acc[8];
#pragma unroll
        for (int nt = 0; nt < 8; ++nt) acc[nt] = (f32x4){0.f, 0.f, 0.f, 0.f};

        const char* Ab = (const char*)As;
        const char* Bb = (const char*)Wt;
#pragma unroll
        for (int kt = 0; kt < 4; ++kt) {
            int kByte = kt * 64 + hi4 * 16;
            f16x8 af = *(const f16x8*)(Ab + swz(wv * 16 + lo16, kByte));
#pragma unroll
            for (int nt = 0; nt < 8; ++nt) {
                f16x8 bf = *(const f16x8*)(Bb + swz(nt * 16 + lo16, kByte));
                acc[nt] = __builtin_amdgcn_mfma_f32_16x16x32_f16(af, bf, acc[nt], 0, 0, 0);
            }
        }

        int rbase = blockIdx.x * 128 + t * 64 + wv * 16 + hi4 * 4;
#pragma unroll
        for (int nt = 0; nt < 8; ++nt) {
#pragma unroll
            for (int r = 0; r < 4; ++r) {
                int node = rbase + r;
                if (node < n)
                    hwout[(size_t)node * 128 + nt * 16 + lo16] = __float2half_rn(acc[nt][r]);
            }
        }
    }
}

// ---------------- pooling: segment_max(relu(agg+b)) via atomicMax on float bits ----------------

__global__ void k_pool_max(const __half* __restrict__ agg, const float* __restrict__ b,
                           const int* __restrict__ batch, unsigned* __restrict__ pooled, int n) {
    int idx = blockIdx.x * 256 + threadIdx.x;
    int node = idx >> 7;
    if (node >= n) return;
    int c = idx & 127;
    int g = batch[node];
    float v = __half2float(agg[(size_t)node * 128 + c]) + b[c];
    v = fmaxf(v, 0.f);
    atomicMax(&pooled[(size_t)g * 128 + c], __float_as_uint(v));
}

// ---------------- head: out[g] = pooled[g] @ Wl + bl ----------------

__global__ void k_final(const float* __restrict__ pooled, const float* __restrict__ Wl,
                        const float* __restrict__ bl, float* __restrict__ out) {
    int g = blockIdx.x;
    int t = threadIdx.x;  // 64 threads
    float p0 = pooled[(size_t)g * 128 + t];
    float p1 = pooled[(size_t)g * 128 + t + 64];
    float a0 = p0 * Wl[t * 2 + 0] + p1 * Wl[(t + 64) * 2 + 0];
    float a1 = p0 * Wl[t * 2 + 1] + p1 * Wl[(t + 64) * 2 + 1];
#pragma unroll
    for (int off = 32; off > 0; off >>= 1) {
        a0 += __shfl_down(a0, off);
        a1 += __shfl_down(a1, off);
    }
    if (t == 0) {
        out[g * 2 + 0] = a0 + bl[0];
        out[g * 2 + 1] = a1 + bl[1];
    }
}

// ---------------- launch ----------------

extern "C" void kernel_launch(void* const* d_in, const int* in_sizes, int n_in,
                              void* d_out, int out_size, void* d_ws, size_t ws_size,
                              hipStream_t stream) {
    const float* x  = (const float*)d_in[0];
    const int*   ei = (const int*)d_in[1];
    const int*   batch = (const int*)d_in[2];
    const float* W1 = (const float*)d_in[3];
    const float* b1 = (const float*)d_in[4];
    const float* W2 = (const float*)d_in[5];
    const float* b2 = (const float*)d_in[6];
    const float* W3 = (const float*)d_in[7];
    const float* b3 = (const float*)d_in[8];
    const float* Wl = (const float*)d_in[9];
    const float* bl = (const float*)d_in[10];
    float* out = (float*)d_out;

    const int N = N_NODES, E = N_EDGES;

    // workspace layout
    char* ws = (char*)d_ws;
    __half* bufA = (__half*)ws;                             // N*128 fp16 (hw)
    __half* bufB = bufA + (size_t)N * 128;                  // N*128 fp16 (agg)
    unsigned* pooled = (unsigned*)(bufB + (size_t)N * 128); // G*128
    float* dis  = (float*)(pooled + (size_t)N_GRAPHS * 128);
    float* dinv = dis + N;
    int*   cnt  = (int*)(dinv + N);                         // N
    int*   rowptr = cnt + N;                                // N+1
    int*   cursor = rowptr + N + 2;                         // N
    int*   bsum   = cursor + N;                             // 512
    int*   csrc   = bsum + 512;                             // E

    int nb256 = (N + 255) / 256;   // 391
    int eb256 = (E + 255) / 256;   // 6250

    // CSR build + norms
    hipMemsetAsync(cnt, 0, (size_t)N * sizeof(int), stream);
    k_hist<<<eb256, 256, 0, stream>>>(ei + E, E, cnt);
    k_deg_fin<<<nb256, 256, 0, stream>>>(cnt, dis, dinv, N);
    k_scan1<<<nb256, SCAN_B, 0, stream>>>(cnt, rowptr, bsum, N);
    k_scan2<<<1, 512, 0, stream>>>(bsum, nb256);
    k_scan3<<<nb256, SCAN_B, 0, stream>>>(rowptr, bsum, cursor, N, E);
    k_scatter<<<eb256, 256, 0, stream>>>(ei, cursor, csrc, E);

    int ggrid = (N + 3) / 4;
    int mfma_grid = (N + 127) / 128;   // 782

    // layer 1
    k_linear1<<<(N + 1) / 2, 256, 0, stream>>>(x, W1, bufA, N);
    k_gather<<<ggrid, 256, 0, stream>>>(rowptr, csrc, dis, dinv,
                                        (const __half2*)bufA, (__half2*)bufB, N);

    // layer 2
    k_gemm_mfma<<<mfma_grid, 256, 0, stream>>>(bufB, b1, W2, bufA, N);
    k_gather<<<ggrid, 256, 0, stream>>>(rowptr, csrc, dis, dinv,
                                        (const __half2*)bufA, (__half2*)bufB, N);

    // layer 3
    k_gemm_mfma<<<mfma_grid, 256, 0, stream>>>(bufB, b2, W3, bufA, N);
    k_gather<<<ggrid, 256, 0, stream>>>(rowptr, csrc, dis, dinv,
                                        (const __half2*)bufA, (__half2*)bufB, N);

    // pooling
    hipMemsetAsync(pooled, 0, (size_t)N_GRAPHS * 128 * sizeof(unsigned), stream);
    k_pool_max<<<(N * 128 + 255) / 256, 256, 0, stream>>>(bufB, b3, batch, pooled, N);

    // head
    k_final<<<N_GRAPHS, 64, 0, stream>>>((const float*)pooled, Wl, bl, out);
}

// Round 8
// 515.410 us; speedup vs baseline: 1.1987x; 1.1987x over previous
//
#include <hip/hip_runtime.h>
#include <hip/hip_fp16.h>

#define N_NODES 100000
#define N_EDGES 1600000
#define HID 128
#define N_GRAPHS 512
#define SCAN_B 256
#define NBK 196      // ceil(N_NODES/512) dst-buckets
#define SEG 8192     // edges per passA block

typedef _Float16 f16x8 __attribute__((ext_vector_type(8)));
typedef float f32x4 __attribute__((ext_vector_type(4)));

// ---------------- degree histogram / norms / prefix scan ----------------

__global__ void k_hist(const int* __restrict__ dst, int e, int* __restrict__ cnt) {
    int i = blockIdx.x * 256 + threadIdx.x;
    if (i < e) atomicAdd(&cnt[dst[i]], 1);
}

__global__ void k_deg_fin(const int* __restrict__ cnt, float* __restrict__ dis,
                          float* __restrict__ dinv, int n) {
    int i = blockIdx.x * 256 + threadIdx.x;
    if (i < n) {
        float d = (float)(cnt[i] + 1);   // +1 self-loop
        dis[i] = rsqrtf(d);
        dinv[i] = 1.0f / d;
    }
}

__global__ void k_scan1(const int* __restrict__ cnt, int* __restrict__ pre,
                        int* __restrict__ bsum, int n) {
    __shared__ int s[SCAN_B];
    int t = threadIdx.x;
    int i = blockIdx.x * SCAN_B + t;
    int v = (i < n) ? cnt[i] : 0;
    s[t] = v;
    __syncthreads();
    for (int off = 1; off < SCAN_B; off <<= 1) {
        int u = (t >= off) ? s[t - off] : 0;
        __syncthreads();
        s[t] += u;
        __syncthreads();
    }
    if (i < n) pre[i] = s[t] - v;                     // exclusive
    if (t == SCAN_B - 1) bsum[blockIdx.x] = s[t];     // block total
}

__global__ void k_scan2(int* __restrict__ bsum, int nb) {
    __shared__ int s[512];
    int t = threadIdx.x;
    int v = (t < nb) ? bsum[t] : 0;
    s[t] = v;
    __syncthreads();
    for (int off = 1; off < 512; off <<= 1) {
        int u = (t >= off) ? s[t - off] : 0;
        __syncthreads();
        s[t] += u;
        __syncthreads();
    }
    if (t < nb) bsum[t] = s[t] - v;                   // exclusive
}

__global__ void k_scan3(int* __restrict__ pre, const int* __restrict__ bsum, int n, int e) {
    int i = blockIdx.x * SCAN_B + threadIdx.x;
    if (i < n) pre[i] += bsum[blockIdx.x];
    if (i == 0) pre[n] = e;
}

// ---------------- CSR build: 2-pass radix partition ----------------
// R6/R7 lesson: one-pass scatter over 6.4MB random positions = every 64B line
// partially written from all 8 XCDs -> ~16x writeback amplification (100MB),
// invariant to store type (plain vs atomicExch). Fix: make write regions
// block-exclusive. PassA partitions edges into 196 dst-range buckets (block
// claims a contiguous chunk per bucket -> coalesced, exclusive). PassB: one
// block per bucket places edges at rowptr[d]+rank via LDS cursors; its whole
// output span (~32KB) is block-exclusive -> lines written once, one XCD.

__global__ void k_binit(const int* __restrict__ rowptr, int* __restrict__ bcur) {
    int b = threadIdx.x;
    if (b < NBK) bcur[b] = rowptr[b * 512];
}

__launch_bounds__(256) __global__
void k_passA(const int* __restrict__ ei, int* __restrict__ bcur,
             unsigned* __restrict__ pk, int e) {
    __shared__ int lcnt[NBK];
    __shared__ int lbase[NBK];
    int tid = threadIdx.x;
    int base = blockIdx.x * SEG;
    for (int i = tid; i < NBK; i += 256) lcnt[i] = 0;
    __syncthreads();
    int m = min(SEG, e - base);
    for (int i = tid; i < m; i += 256) {
        int d = ei[N_EDGES + base + i];
        atomicAdd(&lcnt[d >> 9], 1);
    }
    __syncthreads();
    for (int b = tid; b < NBK; b += 256)
        lbase[b] = lcnt[b] ? atomicAdd(&bcur[b], lcnt[b]) : 0;
    __syncthreads();
    for (int i = tid; i < m; i += 256) {
        int s = ei[base + i];
        int d = ei[N_EDGES + base + i];
        int pos = atomicAdd(&lbase[d >> 9], 1);
        pk[pos] = ((unsigned)s << 9) | (unsigned)(d & 511);   // s<2^17 fits
    }
}

__launch_bounds__(256) __global__
void k_passB(const unsigned* __restrict__ pk, const int* __restrict__ rowptr,
             int* __restrict__ csrc, int n) {
    __shared__ int lcur[512];
    int b = blockIdx.x;
    int tid = threadIdx.x;
    int db0 = b * 512;
    int nd = min(512, n - db0);
    int pbeg = rowptr[db0];
    int pend = rowptr[db0 + nd];
    for (int j = tid; j < nd; j += 256) lcur[j] = rowptr[db0 + j];
    __syncthreads();
    for (int i = pbeg + tid; i < pend; i += 256) {
        unsigned v = pk[i];
        int pos = atomicAdd(&lcur[v & 511], 1);
        csrc[pos] = (int)(v >> 9);
    }
}

// ---------------- layer 1: x (N x 7) @ W1 (7 x 128) -> fp16 ----------------

__global__ void k_linear1(const float* __restrict__ x, const float* __restrict__ W1,
                          __half* __restrict__ hw, int n) {
    __shared__ float W1s[7 * 128];
    int tid = threadIdx.x;
    for (int i = tid; i < 7 * 128; i += 256) W1s[i] = W1[i];
    __syncthreads();
    int node = blockIdx.x * 2 + (tid >> 7);
    if (node >= n) return;
    int c = tid & 127;
    const float* xr = x + (size_t)node * 7;
    float acc = 0.f;
#pragma unroll
    for (int k = 0; k < 7; ++k) acc += xr[k] * W1s[k * 128 + c];
    hw[(size_t)node * 128 + c] = __float2half_rn(acc);
}

// ---------------- gather aggregation (fp16 rows) ----------------
// agg[d] = dinv[d]*hw[d] + dis[d] * sum_s dis[s]*hw[s]
// 2 nodes per wave: lanes 0-31 node A, 32-63 node B; 8B (4 halves) per lane.
// Doubles rows in flight per wave vs 1-node/wave at same unroll depth.
// Grid*8 == N exactly -> no partial waves (shuffle-safe).

__device__ __forceinline__ void acc8(uint2 p, float w, float4& a) {
    float2 lo = __half22float2(*(__half2*)&p.x);
    float2 hi = __half22float2(*(__half2*)&p.y);
    a.x += lo.x * w; a.y += lo.y * w; a.z += hi.x * w; a.w += hi.y * w;
}

__launch_bounds__(256) __global__
void k_gather(const int* __restrict__ rowptr, const int* __restrict__ csrc,
              const float* __restrict__ dis, const float* __restrict__ dinv,
              const uint2* __restrict__ hwv, uint2* __restrict__ aggv, int n) {
    int wid = blockIdx.x * 4 + (threadIdx.x >> 6);
    int lane = threadIdx.x & 63;
    int sub = lane >> 5;          // 0: node A, 1: node B
    int c = lane & 31;            // uint2 column (4 halves)
    int node = wid * 2 + sub;
    if (node >= n) return;        // never taken mid-wave (N multiple of 8*grid step)

    int beg = rowptr[node];
    int end = rowptr[node + 1];
    int deg = end - beg;
    float dd = dis[node];
    float di = dinv[node];

    // cooperative preload: lane c of each half-wave takes edge beg+c
    int sidx = 0;
    float wsc = 0.f;
    if (c < deg) {
        sidx = csrc[beg + c];
        wsc = dis[sidx];
    }

    int mown = deg < 32 ? deg : 32;
    int m = max(__shfl(mown, 0), __shfl(mown, 32));   // wave-uniform bound
    int sub32 = sub << 5;

    float4 a = make_float4(0.f, 0.f, 0.f, 0.f);
    int j = 0;
    for (; j + 3 < m; j += 4) {
        int s0 = __shfl(sidx, sub32 + j);     float w0 = __shfl(wsc, sub32 + j);
        int s1 = __shfl(sidx, sub32 + j + 1); float w1 = __shfl(wsc, sub32 + j + 1);
        int s2 = __shfl(sidx, sub32 + j + 2); float w2 = __shfl(wsc, sub32 + j + 2);
        int s3 = __shfl(sidx, sub32 + j + 3); float w3 = __shfl(wsc, sub32 + j + 3);
        uint2 p0 = hwv[(size_t)s0 * 32 + c];
        uint2 p1 = hwv[(size_t)s1 * 32 + c];
        uint2 p2 = hwv[(size_t)s2 * 32 + c];
        uint2 p3 = hwv[(size_t)s3 * 32 + c];
        acc8(p0, w0, a); acc8(p1, w1, a); acc8(p2, w2, a); acc8(p3, w3, a);
    }
    for (; j < m; ++j) {
        int s0 = __shfl(sidx, sub32 + j);
        float w0 = __shfl(wsc, sub32 + j);
        uint2 p0 = hwv[(size_t)s0 * 32 + c];
        acc8(p0, w0, a);
    }
    // rare tail (deg > 32)
    for (int jj = beg + 32; jj < end; ++jj) {
        int s0 = csrc[jj];
        float w0 = dis[s0];
        uint2 p0 = hwv[(size_t)s0 * 32 + c];
        acc8(p0, w0, a);
    }

    uint2 ps = hwv[(size_t)node * 32 + c];
    float2 slo = __half22float2(*(__half2*)&ps.x);
    float2 shi = __half22float2(*(__half2*)&ps.y);
    float4 r;
    r.x = slo.x * di + dd * a.x;
    r.y = slo.y * di + dd * a.y;
    r.z = shi.x * di + dd * a.z;
    r.w = shi.y * di + dd * a.w;
    __half2 lo = __floats2half2_rn(r.x, r.y);
    __half2 hi = __floats2half2_rn(r.z, r.w);
    uint2 o;
    o.x = *(unsigned*)&lo;
    o.y = *(unsigned*)&hi;
    aggv[(size_t)node * 32 + c] = o;
}

// ---------------- MFMA GEMM: hwout = relu(aggin + b) @ W  (fp16 in/out) ----------------
// 4 waves/block; W^T staged once, two 64-row A-tiles per block. XOR swizzle
// kills bank conflicts. Rows >= n zero-filled (no OOB read of poisoned ws).

__device__ __forceinline__ int swz(int row, int kByte) {
    return row * 256 + (kByte ^ ((row & 7) << 4));
}

__launch_bounds__(256) __global__
void k_gemm_mfma(const __half* __restrict__ aggin, const float* __restrict__ b,
                 const float* __restrict__ W, __half* __restrict__ hwout, int n) {
    __shared__ __align__(16) _Float16 Wt[128 * 128];  // 32 KB
    __shared__ __align__(16) _Float16 As[64 * 128];   // 16 KB
    int tid = threadIdx.x;

    for (int i = tid; i < 128 * 128; i += 256) {
        int k = i >> 7;
        int nn = i & 127;
        *(_Float16*)((char*)Wt + swz(nn, k * 2)) = (_Float16)W[i];
    }

    int row = tid >> 2;
    int q = tid & 3;
    int wv = tid >> 6;
    int lane = tid & 63;
    int lo16 = lane & 15;
    int hi4 = lane >> 4;

    for (int t = 0; t < 2; ++t) {
        if (t) __syncthreads();
        int grow = blockIdx.x * 128 + t * 64 + row;
#pragma unroll
        for (int j = 0; j < 4; ++j) {
            int c0 = q * 32 + j * 8;
            uint4 pk = make_uint4(0u, 0u, 0u, 0u);
            if (grow < n) {
                uint4 p = *(const uint4*)(aggin + (size_t)grow * 128 + c0);
                float4 bA = *(const float4*)(b + c0);
                float4 bB = *(const float4*)(b + c0 + 4);
                float2 t0 = __half22float2(*(const __half2*)&p.x);
                float2 t1 = __half22float2(*(const __half2*)&p.y);
                float2 t2 = __half22float2(*(const __half2*)&p.z);
                float2 t3 = __half22float2(*(const __half2*)&p.w);
                __half2 h0 = __floats2half2_rn(fmaxf(t0.x + bA.x, 0.f), fmaxf(t0.y + bA.y, 0.f));
                __half2 h1 = __floats2half2_rn(fmaxf(t1.x + bA.z, 0.f), fmaxf(t1.y + bA.w, 0.f));
                __half2 h2 = __floats2half2_rn(fmaxf(t2.x + bB.x, 0.f), fmaxf(t2.y + bB.y, 0.f));
                __half2 h3 = __floats2half2_rn(fmaxf(t3.x + bB.z, 0.f), fmaxf(t3.y + bB.w, 0.f));
                pk.x = *(unsigned*)&h0; pk.y = *(unsigned*)&h1;
                pk.z = *(unsigned*)&h2; pk.w = *(unsigned*)&h3;
            }
            *(uint4*)((char*)As + swz(row, c0 * 2)) = pk;
        }
        __syncthreads();

        f32x4 acc[8];
#pragma unroll
        for (int nt = 0; nt < 8; ++nt) acc[nt] = (f32x4){0.f, 0.f, 0.f, 0.f};

        const char* Ab = (const char*)As;
        const char* Bb = (const char*)Wt;
#pragma unroll
        for (int kt = 0; kt < 4; ++kt) {
            int kByte = kt * 64 + hi4 * 16;
            f16x8 af = *(const f16x8*)(Ab + swz(wv * 16 + lo16, kByte));
#pragma unroll
            for (int nt = 0; nt < 8; ++nt) {
                f16x8 bf = *(const f16x8*)(Bb + swz(nt * 16 + lo16, kByte));
                acc[nt] = __builtin_amdgcn_mfma_f32_16x16x32_f16(af, bf, acc[nt], 0, 0, 0);
            }
        }

        int rbase = blockIdx.x * 128 + t * 64 + wv * 16 + hi4 * 4;
#pragma unroll
        for (int nt = 0; nt < 8; ++nt) {
#pragma unroll
            for (int r = 0; r < 4; ++r) {
                int node = rbase + r;
                if (node < n)
                    hwout[(size_t)node * 128 + nt * 16 + lo16] = __float2half_rn(acc[nt][r]);
            }
        }
    }
}

// ---------------- pooling: segment_max(relu(agg+b)) via atomicMax on float bits ----------------

__global__ void k_pool_max(const __half* __restrict__ agg, const float* __restrict__ b,
                           const int* __restrict__ batch, unsigned* __restrict__ pooled, int n) {
    int idx = blockIdx.x * 256 + threadIdx.x;
    int node = idx >> 7;
    if (node >= n) return;
    int c = idx & 127;
    int g = batch[node];
    float v = __half2float(agg[(size_t)node * 128 + c]) + b[c];
    v = fmaxf(v, 0.f);
    atomicMax(&pooled[(size_t)g * 128 + c], __float_as_uint(v));
}

// ---------------- head: out[g] = pooled[g] @ Wl + bl ----------------

__global__ void k_final(const float* __restrict__ pooled, const float* __restrict__ Wl,
                        const float* __restrict__ bl, float* __restrict__ out) {
    int g = blockIdx.x;
    int t = threadIdx.x;  // 64 threads
    float p0 = pooled[(size_t)g * 128 + t];
    float p1 = pooled[(size_t)g * 128 + t + 64];
    float a0 = p0 * Wl[t * 2 + 0] + p1 * Wl[(t + 64) * 2 + 0];
    float a1 = p0 * Wl[t * 2 + 1] + p1 * Wl[(t + 64) * 2 + 1];
#pragma unroll
    for (int off = 32; off > 0; off >>= 1) {
        a0 += __shfl_down(a0, off);
        a1 += __shfl_down(a1, off);
    }
    if (t == 0) {
        out[g * 2 + 0] = a0 + bl[0];
        out[g * 2 + 1] = a1 + bl[1];
    }
}

// ---------------- launch ----------------

extern "C" void kernel_launch(void* const* d_in, const int* in_sizes, int n_in,
                              void* d_out, int out_size, void* d_ws, size_t ws_size,
                              hipStream_t stream) {
    const float* x  = (const float*)d_in[0];
    const int*   ei = (const int*)d_in[1];
    const int*   batch = (const int*)d_in[2];
    const float* W1 = (const float*)d_in[3];
    const float* b1 = (const float*)d_in[4];
    const float* W2 = (const float*)d_in[5];
    const float* b2 = (const float*)d_in[6];
    const float* W3 = (const float*)d_in[7];
    const float* b3 = (const float*)d_in[8];
    const float* Wl = (const float*)d_in[9];
    const float* bl = (const float*)d_in[10];
    float* out = (float*)d_out;

    const int N = N_NODES, E = N_EDGES;

    // workspace layout
    char* ws = (char*)d_ws;
    __half* bufA = (__half*)ws;                             // N*128 fp16 (hw)
    __half* bufB = bufA + (size_t)N * 128;                  // N*128 fp16 (agg)
    unsigned* pooled = (unsigned*)(bufB + (size_t)N * 128); // G*128
    float* dis  = (float*)(pooled + (size_t)N_GRAPHS * 128);
    float* dinv = dis + N;
    int*   cnt  = (int*)(dinv + N);                         // N
    int*   rowptr = cnt + N;                                // N+1
    int*   bcur   = rowptr + N + 2;                         // NBK (reuses old cursor slot)
    int*   bsum   = bcur + N;                               // 512
    int*   csrc   = bsum + 512;                             // E
    unsigned* pk  = (unsigned*)(csrc + E);                  // E

    int nb256 = (N + 255) / 256;   // 391
    int eb256 = (E + 255) / 256;   // 6250

    // CSR build + norms (2-pass radix partition)
    hipMemsetAsync(cnt, 0, (size_t)N * sizeof(int), stream);
    k_hist<<<eb256, 256, 0, stream>>>(ei + E, E, cnt);
    k_deg_fin<<<nb256, 256, 0, stream>>>(cnt, dis, dinv, N);
    k_scan1<<<nb256, SCAN_B, 0, stream>>>(cnt, rowptr, bsum, N);
    k_scan2<<<1, 512, 0, stream>>>(bsum, nb256);
    k_scan3<<<nb256, SCAN_B, 0, stream>>>(rowptr, bsum, N, E);
    k_binit<<<1, 256, 0, stream>>>(rowptr, bcur);
    k_passA<<<(E + SEG - 1) / SEG, 256, 0, stream>>>(ei, bcur, pk, E);
    k_passB<<<NBK, 256, 0, stream>>>(pk, rowptr, csrc, N);

    int ggrid = (N + 7) / 8;           // 2 nodes/wave, 4 waves/block
    int mfma_grid = (N + 127) / 128;   // 782

    // layer 1
    k_linear1<<<(N + 1) / 2, 256, 0, stream>>>(x, W1, bufA, N);
    k_gather<<<ggrid, 256, 0, stream>>>(rowptr, csrc, dis, dinv,
                                        (const uint2*)bufA, (uint2*)bufB, N);

    // layer 2
    k_gemm_mfma<<<mfma_grid, 256, 0, stream>>>(bufB, b1, W2, bufA, N);
    k_gather<<<ggrid, 256, 0, stream>>>(rowptr, csrc, dis, dinv,
                                        (const uint2*)bufA, (uint2*)bufB, N);

    // layer 3
    k_gemm_mfma<<<mfma_grid, 256, 0, stream>>>(bufB, b2, W3, bufA, N);
    k_gather<<<ggrid, 256, 0, stream>>>(rowptr, csrc, dis, dinv,
                                        (const uint2*)bufA, (uint2*)bufB, N);

    // pooling
    hipMemsetAsync(pooled, 0, (size_t)N_GRAPHS * 128 * sizeof(unsigned), stream);
    k_pool_max<<<(N * 128 + 255) / 256, 256, 0, stream>>>(bufB, b3, batch, pooled, N);

    // head
    k_final<<<N_GRAPHS, 64, 0, stream>>>((const float*)pooled, Wl, bl, out);
}

// Round 9
// 459.302 us; speedup vs baseline: 1.3451x; 1.1222x over previous
//
#include <hip/hip_runtime.h>
#include <hip/hip_fp16.h>

#define N_NODES 100000
#define N_EDGES 1600000
#define HID 128
#define N_GRAPHS 512
#define NBK 196      // ceil(N_NODES/512) dst-buckets
#define SEG 8192     // edges per bhist/passA block

typedef _Float16 f16x8 __attribute__((ext_vector_type(8)));
typedef float f32x4 __attribute__((ext_vector_type(4)));

// ---------------- CSR build: bucket histogram -> scan -> 2-pass radix ----------------
// R6-R8 lessons: (a) random 4B stores/atomics to HBM-shared lines cost a full
// 64B line writeback per op (8 non-coherent XCD L2s churn ownership) — R8's
// k_hist: 1.6M atomics over 400KB -> 50MB WRITE, 70µs. (b) Fix = keep counts
// in LDS and make every global write region block-exclusive & coalesced.
// So: per-node histogram/scan/rowptr/dis/dinv all move into k_passB where the
// bucket's 512 counters live in LDS.

__global__ void k_bhist(const int* __restrict__ dst, int e, int* __restrict__ bkcnt) {
    __shared__ int l[NBK];
    int tid = threadIdx.x;
    for (int i = tid; i < NBK; i += 256) l[i] = 0;
    __syncthreads();
    int base = blockIdx.x * SEG;
    int m = min(SEG, e - base);
    for (int i = tid; i < m; i += 256) atomicAdd(&l[dst[base + i] >> 9], 1);
    __syncthreads();
    for (int b = tid; b < NBK; b += 256)
        if (l[b]) atomicAdd(&bkcnt[b], l[b]);
}

// single block: exclusive scan of 196 bucket counts -> bkoff[197], init bcur
__global__ void k_bscan(const int* __restrict__ bkcnt, int* __restrict__ bkoff,
                        int* __restrict__ bcur, int e) {
    __shared__ int s[256];
    int t = threadIdx.x;
    int v = (t < NBK) ? bkcnt[t] : 0;
    s[t] = v;
    __syncthreads();
    for (int off = 1; off < 256; off <<= 1) {
        int u = (t >= off) ? s[t - off] : 0;
        __syncthreads();
        s[t] += u;
        __syncthreads();
    }
    int excl = s[t] - v;
    if (t < NBK) { bkoff[t] = excl; bcur[t] = excl; }
    if (t == NBK - 1) bkoff[NBK] = excl + v;   // == e
}

__launch_bounds__(256) __global__
void k_passA(const int* __restrict__ ei, int* __restrict__ bcur,
             unsigned* __restrict__ pk, int e) {
    __shared__ int lcnt[NBK];
    __shared__ int lbase[NBK];
    int tid = threadIdx.x;
    int base = blockIdx.x * SEG;
    for (int i = tid; i < NBK; i += 256) lcnt[i] = 0;
    __syncthreads();
    int m = min(SEG, e - base);
    for (int i = tid; i < m; i += 256) {
        int d = ei[N_EDGES + base + i];
        atomicAdd(&lcnt[d >> 9], 1);
    }
    __syncthreads();
    for (int b = tid; b < NBK; b += 256)
        lbase[b] = lcnt[b] ? atomicAdd(&bcur[b], lcnt[b]) : 0;
    __syncthreads();
    for (int i = tid; i < m; i += 256) {
        int s = ei[base + i];
        int d = ei[N_EDGES + base + i];
        int pos = atomicAdd(&lbase[d >> 9], 1);
        pk[pos] = ((unsigned)s << 9) | (unsigned)(d & 511);   // s<2^17 fits
    }
}

// one block per bucket: per-node LDS histogram -> LDS scan -> rowptr/dis/dinv
// (block-exclusive coalesced writes) -> place edges via LDS cursors.
__launch_bounds__(256) __global__
void k_passB(const unsigned* __restrict__ pk, const int* __restrict__ bkoff,
             int* __restrict__ rowptr, float* __restrict__ dis, float* __restrict__ dinv,
             int* __restrict__ csrc, int n, int e) {
    __shared__ int lcnt[512];
    __shared__ int lofs[512];
    __shared__ int sw[256];
    int b = blockIdx.x;
    int tid = threadIdx.x;
    int db0 = b * 512;
    int nd = min(512, n - db0);
    int pbeg = bkoff[b];
    int pend = bkoff[b + 1];
    lcnt[tid] = 0;
    lcnt[tid + 256] = 0;
    __syncthreads();
    for (int i = pbeg + tid; i < pend; i += 256) atomicAdd(&lcnt[pk[i] & 511], 1);
    __syncthreads();
    // degree outputs (deg = in-count + 1 self-loop)
    for (int j = tid; j < nd; j += 256) {
        float d = (float)(lcnt[j] + 1);
        dis[db0 + j] = rsqrtf(d);
        dinv[db0 + j] = 1.0f / d;
    }
    // exclusive scan of 512 counts: pairwise + Hillis-Steele over 256
    int a0 = lcnt[2 * tid];
    int a1 = lcnt[2 * tid + 1];
    int v = a0 + a1;
    sw[tid] = v;
    __syncthreads();
    for (int off = 1; off < 256; off <<= 1) {
        int u = (tid >= off) ? sw[tid - off] : 0;
        __syncthreads();
        sw[tid] += u;
        __syncthreads();
    }
    int excl = sw[tid] - v;
    lofs[2 * tid] = excl;
    lofs[2 * tid + 1] = excl + a0;
    __syncthreads();
    for (int j = tid; j < nd; j += 256) rowptr[db0 + j] = pbeg + lofs[j];
    if (db0 + nd == n && tid == 0) rowptr[n] = e;
    // reuse lcnt as global cursors
    for (int j = tid; j < 512; j += 256) lcnt[j] = pbeg + lofs[j];
    __syncthreads();
    for (int i = pbeg + tid; i < pend; i += 256) {
        unsigned w = pk[i];
        int pos = atomicAdd(&lcnt[w & 511], 1);
        csrc[pos] = (int)(w >> 9);
    }
}

// ---------------- layer 1: x (N x 7) @ W1 (7 x 128) -> fp16 ----------------

__global__ void k_linear1(const float* __restrict__ x, const float* __restrict__ W1,
                          __half* __restrict__ hw, int n) {
    __shared__ float W1s[7 * 128];
    int tid = threadIdx.x;
    for (int i = tid; i < 7 * 128; i += 256) W1s[i] = W1[i];
    __syncthreads();
    int node = blockIdx.x * 2 + (tid >> 7);
    if (node >= n) return;
    int c = tid & 127;
    const float* xr = x + (size_t)node * 7;
    float acc = 0.f;
#pragma unroll
    for (int k = 0; k < 7; ++k) acc += xr[k] * W1s[k * 128 + c];
    hw[(size_t)node * 128 + c] = __float2half_rn(acc);
}

// ---------------- gather aggregation (fp16 rows) ----------------
// agg[d] = dinv[d]*hw[d] + dis[d] * sum_s dis[s]*hw[s]
// 2 nodes per wave; 8B per lane; cooperative preload + __shfl broadcast.

__device__ __forceinline__ void acc8(uint2 p, float w, float4& a) {
    float2 lo = __half22float2(*(__half2*)&p.x);
    float2 hi = __half22float2(*(__half2*)&p.y);
    a.x += lo.x * w; a.y += lo.y * w; a.z += hi.x * w; a.w += hi.y * w;
}

__launch_bounds__(256) __global__
void k_gather(const int* __restrict__ rowptr, const int* __restrict__ csrc,
              const float* __restrict__ dis, const float* __restrict__ dinv,
              const uint2* __restrict__ hwv, uint2* __restrict__ aggv, int n) {
    int wid = blockIdx.x * 4 + (threadIdx.x >> 6);
    int lane = threadIdx.x & 63;
    int sub = lane >> 5;          // 0: node A, 1: node B
    int c = lane & 31;            // uint2 column (4 halves)
    int node = wid * 2 + sub;
    if (node >= n) return;        // never taken mid-wave

    int beg = rowptr[node];
    int end = rowptr[node + 1];
    int deg = end - beg;
    float dd = dis[node];
    float di = dinv[node];

    int sidx = 0;
    float wsc = 0.f;
    if (c < deg) {
        sidx = csrc[beg + c];
        wsc = dis[sidx];
    }

    int mown = deg < 32 ? deg : 32;
    int m = max(__shfl(mown, 0), __shfl(mown, 32));
    int sub32 = sub << 5;

    float4 a = make_float4(0.f, 0.f, 0.f, 0.f);
    int j = 0;
    for (; j + 3 < m; j += 4) {
        int s0 = __shfl(sidx, sub32 + j);     float w0 = __shfl(wsc, sub32 + j);
        int s1 = __shfl(sidx, sub32 + j + 1); float w1 = __shfl(wsc, sub32 + j + 1);
        int s2 = __shfl(sidx, sub32 + j + 2); float w2 = __shfl(wsc, sub32 + j + 2);
        int s3 = __shfl(sidx, sub32 + j + 3); float w3 = __shfl(wsc, sub32 + j + 3);
        uint2 p0 = hwv[(size_t)s0 * 32 + c];
        uint2 p1 = hwv[(size_t)s1 * 32 + c];
        uint2 p2 = hwv[(size_t)s2 * 32 + c];
        uint2 p3 = hwv[(size_t)s3 * 32 + c];
        acc8(p0, w0, a); acc8(p1, w1, a); acc8(p2, w2, a); acc8(p3, w3, a);
    }
    for (; j < m; ++j) {
        int s0 = __shfl(sidx, sub32 + j);
        float w0 = __shfl(wsc, sub32 + j);
        uint2 p0 = hwv[(size_t)s0 * 32 + c];
        acc8(p0, w0, a);
    }
    for (int jj = beg + 32; jj < end; ++jj) {
        int s0 = csrc[jj];
        float w0 = dis[s0];
        uint2 p0 = hwv[(size_t)s0 * 32 + c];
        acc8(p0, w0, a);
    }

    uint2 ps = hwv[(size_t)node * 32 + c];
    float2 slo = __half22float2(*(__half2*)&ps.x);
    float2 shi = __half22float2(*(__half2*)&ps.y);
    float4 r;
    r.x = slo.x * di + dd * a.x;
    r.y = slo.y * di + dd * a.y;
    r.z = shi.x * di + dd * a.z;
    r.w = shi.y * di + dd * a.w;
    __half2 lo = __floats2half2_rn(r.x, r.y);
    __half2 hi = __floats2half2_rn(r.z, r.w);
    uint2 o;
    o.x = *(unsigned*)&lo;
    o.y = *(unsigned*)&hi;
    aggv[(size_t)node * 32 + c] = o;
}

// ---------------- MFMA GEMM: hwout = relu(aggin + b) @ W  (fp16 in/out) ----------------

__device__ __forceinline__ int swz(int row, int kByte) {
    return row * 256 + (kByte ^ ((row & 7) << 4));
}

__launch_bounds__(256) __global__
void k_gemm_mfma(const __half* __restrict__ aggin, const float* __restrict__ b,
                 const float* __restrict__ W, __half* __restrict__ hwout, int n) {
    __shared__ __align__(16) _Float16 Wt[128 * 128];  // 32 KB
    __shared__ __align__(16) _Float16 As[64 * 128];   // 16 KB
    int tid = threadIdx.x;

    for (int i = tid; i < 128 * 128; i += 256) {
        int k = i >> 7;
        int nn = i & 127;
        *(_Float16*)((char*)Wt + swz(nn, k * 2)) = (_Float16)W[i];
    }

    int row = tid >> 2;
    int q = tid & 3;
    int wv = tid >> 6;
    int lane = tid & 63;
    int lo16 = lane & 15;
    int hi4 = lane >> 4;

    for (int t = 0; t < 2; ++t) {
        if (t) __syncthreads();
        int grow = blockIdx.x * 128 + t * 64 + row;
#pragma unroll
        for (int j = 0; j < 4; ++j) {
            int c0 = q * 32 + j * 8;
            uint4 pk = make_uint4(0u, 0u, 0u, 0u);
            if (grow < n) {
                uint4 p = *(const uint4*)(aggin + (size_t)grow * 128 + c0);
                float4 bA = *(const float4*)(b + c0);
                float4 bB = *(const float4*)(b + c0 + 4);
                float2 t0 = __half22float2(*(const __half2*)&p.x);
                float2 t1 = __half22float2(*(const __half2*)&p.y);
                float2 t2 = __half22float2(*(const __half2*)&p.z);
                float2 t3 = __half22float2(*(const __half2*)&p.w);
                __half2 h0 = __floats2half2_rn(fmaxf(t0.x + bA.x, 0.f), fmaxf(t0.y + bA.y, 0.f));
                __half2 h1 = __floats2half2_rn(fmaxf(t1.x + bA.z, 0.f), fmaxf(t1.y + bA.w, 0.f));
                __half2 h2 = __floats2half2_rn(fmaxf(t2.x + bB.x, 0.f), fmaxf(t2.y + bB.y, 0.f));
                __half2 h3 = __floats2half2_rn(fmaxf(t3.x + bB.z, 0.f), fmaxf(t3.y + bB.w, 0.f));
                pk.x = *(unsigned*)&h0; pk.y = *(unsigned*)&h1;
                pk.z = *(unsigned*)&h2; pk.w = *(unsigned*)&h3;
            }
            *(uint4*)((char*)As + swz(row, c0 * 2)) = pk;
        }
        __syncthreads();

        f32x4 acc[8];
#pragma unroll
        for (int nt = 0; nt < 8; ++nt) acc[nt] = (f32x4){0.f, 0.f, 0.f, 0.f};

        const char* Ab = (const char*)As;
        const char* Bb = (const char*)Wt;
#pragma unroll
        for (int kt = 0; kt < 4; ++kt) {
            int kByte = kt * 64 + hi4 * 16;
            f16x8 af = *(const f16x8*)(Ab + swz(wv * 16 + lo16, kByte));
#pragma unroll
            for (int nt = 0; nt < 8; ++nt) {
                f16x8 bf = *(const f16x8*)(Bb + swz(nt * 16 + lo16, kByte));
                acc[nt] = __builtin_amdgcn_mfma_f32_16x16x32_f16(af, bf, acc[nt], 0, 0, 0);
            }
        }

        int rbase = blockIdx.x * 128 + t * 64 + wv * 16 + hi4 * 4;
#pragma unroll
        for (int nt = 0; nt < 8; ++nt) {
#pragma unroll
            for (int r = 0; r < 4; ++r) {
                int node = rbase + r;
                if (node < n)
                    hwout[(size_t)node * 128 + nt * 16 + lo16] = __float2half_rn(acc[nt][r]);
            }
        }
    }
}

// ---------------- pooling: segment_max(relu(agg+b)) via atomicMax on float bits ----------------

__global__ void k_pool_max(const __half* __restrict__ agg, const float* __restrict__ b,
                           const int* __restrict__ batch, unsigned* __restrict__ pooled, int n) {
    int idx = blockIdx.x * 256 + threadIdx.x;
    int node = idx >> 7;
    if (node >= n) return;
    int c = idx & 127;
    int g = batch[node];
    float v = __half2float(agg[(size_t)node * 128 + c]) + b[c];
    v = fmaxf(v, 0.f);
    atomicMax(&pooled[(size_t)g * 128 + c], __float_as_uint(v));
}

// ---------------- head: out[g] = pooled[g] @ Wl + bl ----------------

__global__ void k_final(const float* __restrict__ pooled, const float* __restrict__ Wl,
                        const float* __restrict__ bl, float* __restrict__ out) {
    int g = blockIdx.x;
    int t = threadIdx.x;  // 64 threads
    float p0 = pooled[(size_t)g * 128 + t];
    float p1 = pooled[(size_t)g * 128 + t + 64];
    float a0 = p0 * Wl[t * 2 + 0] + p1 * Wl[(t + 64) * 2 + 0];
    float a1 = p0 * Wl[t * 2 + 1] + p1 * Wl[(t + 64) * 2 + 1];
#pragma unroll
    for (int off = 32; off > 0; off >>= 1) {
        a0 += __shfl_down(a0, off);
        a1 += __shfl_down(a1, off);
    }
    if (t == 0) {
        out[g * 2 + 0] = a0 + bl[0];
        out[g * 2 + 1] = a1 + bl[1];
    }
}

// ---------------- launch ----------------

extern "C" void kernel_launch(void* const* d_in, const int* in_sizes, int n_in,
                              void* d_out, int out_size, void* d_ws, size_t ws_size,
                              hipStream_t stream) {
    const float* x  = (const float*)d_in[0];
    const int*   ei = (const int*)d_in[1];
    const int*   batch = (const int*)d_in[2];
    const float* W1 = (const float*)d_in[3];
    const float* b1 = (const float*)d_in[4];
    const float* W2 = (const float*)d_in[5];
    const float* b2 = (const float*)d_in[6];
    const float* W3 = (const float*)d_in[7];
    const float* b3 = (const float*)d_in[8];
    const float* Wl = (const float*)d_in[9];
    const float* bl = (const float*)d_in[10];
    float* out = (float*)d_out;

    const int N = N_NODES, E = N_EDGES;

    // workspace layout
    char* ws = (char*)d_ws;
    __half* bufA = (__half*)ws;                             // N*128 fp16 (hw)
    __half* bufB = bufA + (size_t)N * 128;                  // N*128 fp16 (agg)
    unsigned* pooled = (unsigned*)(bufB + (size_t)N * 128); // G*128
    float* dis  = (float*)(pooled + (size_t)N_GRAPHS * 128);
    float* dinv = dis + N;
    int*   rowptr = (int*)(dinv + N);                       // N+1
    int*   bkcnt  = rowptr + N + 2;                         // NBK
    int*   bkoff  = bkcnt + 256;                            // NBK+1
    int*   bcur   = bkoff + 256;                            // NBK
    int*   csrc   = bcur + 256;                             // E
    unsigned* pk  = (unsigned*)(csrc + E);                  // E

    // CSR build + norms (bucket hist -> scan -> radix passA/passB)
    hipMemsetAsync(bkcnt, 0, NBK * sizeof(int), stream);
    int nseg = (E + SEG - 1) / SEG;   // 196
    k_bhist<<<nseg, 256, 0, stream>>>(ei + E, E, bkcnt);
    k_bscan<<<1, 256, 0, stream>>>(bkcnt, bkoff, bcur, E);
    k_passA<<<nseg, 256, 0, stream>>>(ei, bcur, pk, E);
    k_passB<<<NBK, 256, 0, stream>>>(pk, bkoff, rowptr, dis, dinv, csrc, N, E);

    int ggrid = (N + 7) / 8;           // 2 nodes/wave, 4 waves/block
    int mfma_grid = (N + 127) / 128;   // 782

    // layer 1
    k_linear1<<<(N + 1) / 2, 256, 0, stream>>>(x, W1, bufA, N);
    k_gather<<<ggrid, 256, 0, stream>>>(rowptr, csrc, dis, dinv,
                                        (const uint2*)bufA, (uint2*)bufB, N);

    // layer 2
    k_gemm_mfma<<<mfma_grid, 256, 0, stream>>>(bufB, b1, W2, bufA, N);
    k_gather<<<ggrid, 256, 0, stream>>>(rowptr, csrc, dis, dinv,
                                        (const uint2*)bufA, (uint2*)bufB, N);

    // layer 3
    k_gemm_mfma<<<mfma_grid, 256, 0, stream>>>(bufB, b2, W3, bufA, N);
    k_gather<<<ggrid, 256, 0, stream>>>(rowptr, csrc, dis, dinv,
                                        (const uint2*)bufA, (uint2*)bufB, N);

    // pooling
    hipMemsetAsync(pooled, 0, (size_t)N_GRAPHS * 128 * sizeof(unsigned), stream);
    k_pool_max<<<(N * 128 + 255) / 256, 256, 0, stream>>>(bufB, b3, batch, pooled, N);

    // head
    k_final<<<N_GRAPHS, 64, 0, stream>>>((const float*)pooled, Wl, bl, out);
}